// Round 11
// baseline (181.332 us; speedup 1.0000x reference)
//
#include <hip/hip_runtime.h>

typedef unsigned int u32;
typedef unsigned long long u64;
typedef unsigned short u16;
typedef float v2f __attribute__((ext_vector_type(2)));

#define DEV __device__ __forceinline__

// ---------- helpers ----------
DEV u16 f2bf(float x) {                      // fp32 -> bf16 RNE
  u32 u = __float_as_uint(x);
  u32 r = u + 0x7fffu + ((u >> 16) & 1u);
  return (u16)(r >> 16);
}
DEV float bflo(u32 d) { return __uint_as_float(d << 16); }
DEV float bfhi(u32 d) { return __uint_as_float(d & 0xffff0000u); }
DEV u64 sortable64(double f) {               // monotonic f64 -> u64
  long long b = __double_as_longlong(f);
  return (u64)b ^ (u64)((b >> 63) | (long long)0x8000000000000000ll);
}
// fp64 exact-selection distance (float products are exact in f64)
DEV double ddist(double qx, double qy, double qz, double qd2,
                 float mxf, float myf, float mzf) {
  double cx = (double)mxf, cy = (double)myf, cz = (double)mzf;
  double cd2 = cx * cx + cy * cy + cz * cz;
  double dot = cx * qx + cy * qy + cz * qz;
  return (qd2 + cd2) - 2.0 * dot;
}
DEV v2f vfma2(v2f a, v2f b, v2f c) { return __builtin_elementwise_fma(a, b, c); }
DEV v2f vmin2(v2f a, v2f b) { return __builtin_elementwise_min(a, b); }

#define NB 2
#define NN 8192
#define NC 128
#define KK 21
// screening metric: st = cd2 - 2*dot (qd2 dropped — per-query constant shift).
// fp32 error vs fp64 <= ~2e-4 on these operand scales; MARGIN covers it so the
// fp64 top-21 set provably survives fp32 screening.
#define MARGIN 1e-3f

// ---------- kA: fused prep + exact KNN ----------
// r7 single-stage structure (stage all 8192 cands once, 3 barriers) with the
// LDS-pipe halved: 16 waves = 8 query-octets x 2 candidate-halves; each
// ds_read_b128 feeds 8 queries (was 4) -> per-CU ds_read time 20.5->10.2us.
// Eval packed 2-queries-per-fma via v2f (hoping v_pk_fma_f32; scalarization
// is cost-neutral). Per-half threshold = 21st of 64 disjoint lane minima
// (valid upper bound within half), min-merged across halves (+1 barrier).
// Selection (fp64 exact) unchanged -> deterministic output.
__global__ __launch_bounds__(1024) void k_knnprep(
    const float* __restrict__ xyz, int* __restrict__ knn,
    const float* __restrict__ Wf, const float* __restrict__ gf, const float* __restrict__ bf_,
    const float* __restrict__ mf, const float* __restrict__ vf,
    const float* __restrict__ Wg, const float* __restrict__ gg, const float* __restrict__ bg,
    const float* __restrict__ mg, const float* __restrict__ vg,
    u16* __restrict__ Wt, float* __restrict__ beta_f,
    float* __restrict__ Wgu, float* __restrict__ Wgv, float* __restrict__ beta_g) {
  __shared__ float4 sc[NN];                   // 128 KB: all candidates (x,y,z,d2)
  __shared__ u16 ssurv[64][128];              // 16 KB
  __shared__ u32 scnt[64];
  __shared__ float sthr[2][64];               // per-half thresholds

  const int t = threadIdx.x;

  if (blockIdx.x < 32) {                      // ---- prep role ----
    int g = (blockIdx.x << 10) + t;           // 0..32767
    int c = g >> 8, o = g & 255;
    float val;
    if (o < 128) {
      float inv = gf[o] / sqrtf(vf[o] + 1e-5f);
      val = inv * (Wf[o * 256 + c] - Wf[o * 256 + c + 128]);
    } else {
      int o2 = o - 128;
      float inv = gf[o2] / sqrtf(vf[o2] + 1e-5f);
      val = inv * Wf[o2 * 256 + c + 128];
    }
    Wt[c * 256 + o] = f2bf(val);
    if (g < 128) {
      float inv = gf[g] / sqrtf(vf[g] + 1e-5f);
      beta_f[g] = bf_[g] - mf[g] * inv;
    } else if (g < 256) {
      int oo = g - 128;
      float invg = gg[oo] / sqrtf(vg[oo] + 1e-5f);
#pragma unroll
      for (int d = 0; d < 3; ++d) {
        Wgu[oo * 3 + d] = invg * (Wg[oo * 6 + d] - Wg[oo * 6 + 3 + d]);
        Wgv[oo * 3 + d] = invg * Wg[oo * 6 + 3 + d];
      }
      beta_g[oo] = bg[oo] - mg[oo] * invg;
    }
    return;
  }

  // ---- KNN role ----
  const int kb = blockIdx.x - 32;             // 0..255
  const int b = kb >> 7;                      // 128 blocks per batch
  const int n0 = (kb & 127) << 6;             // 64 queries per block
  const float* X = xyz + b * (NN * 3);

  if (t < 64) scnt[t] = 0u;

  const int w = t >> 6, lane = t & 63;        // w = 0..15
  const int g = w & 7;                        // query octet (8 queries)
  const int h = w >> 3;                       // candidate half (0/1)
  const int cbase = h << 12;                  // 0 or 4096
  const int q8 = n0 + (g << 3);

  // 8 query coords per wave, packed in pairs; fold -2x for the fma chain
  v2f mxp[4], myp[4], mzp[4], mnp[4];
#pragma unroll
  for (int j = 0; j < 4; ++j) {
    int qa = q8 + 2 * j, qb = qa + 1;
    mxp[j] = (v2f){-2.0f * X[qa * 3], -2.0f * X[qb * 3]};
    myp[j] = (v2f){-2.0f * X[qa * 3 + 1], -2.0f * X[qb * 3 + 1]};
    mzp[j] = (v2f){-2.0f * X[qa * 3 + 2], -2.0f * X[qb * 3 + 2]};
    mnp[j] = (v2f){__builtin_inff(), __builtin_inff()};
  }

  // stage ALL candidates once (identical fma chain as before -> same bits)
#pragma unroll
  for (int k = 0; k < 8; ++k) {
    int c = (k << 10) + t;
    float x = X[c * 3], y = X[c * 3 + 1], z = X[c * 3 + 2];
    float d2 = __builtin_fmaf(x, x, __builtin_fmaf(y, y, z * z));
    sc[c] = make_float4(x, y, z, d2);
  }
  __syncthreads();                            // barrier #1 (of 3)

  // ---- pass A: per-lane running min over this wave's half, 8 queries ----
#pragma unroll 4
  for (int cc = 0; cc < NN / 2; cc += 64) {
    float4 C = sc[cbase + cc + lane];
    v2f cx = (v2f){C.x, C.x}, cy = (v2f){C.y, C.y};
    v2f cz = (v2f){C.z, C.z}, cw = (v2f){C.w, C.w};
#pragma unroll
    for (int j = 0; j < 4; ++j) {
      v2f s = vfma2(cx, mxp[j], vfma2(cy, myp[j], vfma2(cz, mzp[j], cw)));
      mnp[j] = vmin2(mnp[j], s);
    }
  }

  // ---- per-half threshold: 21st smallest of 64 disjoint lane minima ----
#pragma unroll
  for (int j = 0; j < 4; ++j) {
#pragma unroll
    for (int e = 0; e < 2; ++e) {
      float v = e ? mnp[j].y : mnp[j].x;
#pragma unroll
      for (int k = 2; k <= 64; k <<= 1) {
#pragma unroll
        for (int jj = k >> 1; jj > 0; jj >>= 1) {
          float p = __shfl_xor(v, jj);
          bool takeMin = (((lane & k) == 0) == ((lane & jj) == 0));
          v = takeMin ? fminf(v, p) : fmaxf(v, p);
        }
      }
      float tw = __shfl(v, 20);
      if (lane == 0) sthr[h][(g << 3) + 2 * j + e] = tw;
    }
  }
  __syncthreads();                            // barrier #2 (of 3): merge halves
  float thr[8];
#pragma unroll
  for (int i = 0; i < 8; ++i) {
    int qq = (g << 3) + i;
    thr[i] = fminf(sthr[0][qq], sthr[1][qq]) + MARGIN;
  }

  // ---- pass B: compact survivors (sc resident; same staged bits) ----
#pragma unroll 2
  for (int cc = 0; cc < NN / 2; cc += 64) {
    float4 C = sc[cbase + cc + lane];
    v2f cx = (v2f){C.x, C.x}, cy = (v2f){C.y, C.y};
    v2f cz = (v2f){C.z, C.z}, cw = (v2f){C.w, C.w};
    int mbase = cbase + cc + lane;
#pragma unroll
    for (int j = 0; j < 4; ++j) {
      v2f s = vfma2(cx, mxp[j], vfma2(cy, myp[j], vfma2(cz, mzp[j], cw)));
      int qa = (g << 3) + 2 * j, qb = qa + 1;
      if (s.x <= thr[2 * j] || s.y <= thr[2 * j + 1]) {   // rare-taken
        if (s.x <= thr[2 * j]) {
          u32 slot = atomicAdd(&scnt[qa], 1u);
          if (slot < 128u) ssurv[qa][slot] = (u16)mbase;
        }
        if (s.y <= thr[2 * j + 1]) {
          u32 slot = atomicAdd(&scnt[qb], 1u);
          if (slot < 128u) ssurv[qb][slot] = (u16)mbase;
        }
      }
    }
  }
  __syncthreads();                            // barrier #3 (of 3)

  // ---- selection: exact top-21 by fp64 (dist, idx); 4 queries per wave ----
#pragma unroll 1
  for (int i = 0; i < 4; ++i) {
    const int qq = (w << 2) + i;
    const int q = n0 + qq;
    double Qx = (double)X[q * 3], Qy = (double)X[q * 3 + 1], Qz = (double)X[q * 3 + 2];
    double Qd2 = Qx * Qx + Qy * Qy + Qz * Qz;
    u32 cnt = scnt[qq];
    if (cnt > 128u) cnt = 128u;
    int* outp = knn + ((b << 13) + q) * KK;

    bool v0 = ((u32)lane < cnt);
    u32 m0 = v0 ? (u32)ssurv[qq][lane] : 0u;
    double s0 = ddist(Qx, Qy, Qz, Qd2, X[m0 * 3], X[m0 * 3 + 1], X[m0 * 3 + 2]);
    // key: fp64-sortable, low 13 bits replaced by idx (lowest-index tie-break)
    u64 k0 = v0 ? ((sortable64(s0) & 0xFFFFFFFFFFFFE000ull) | (u64)m0) : ~0ull;

    if (cnt <= 64u) {
      u64 v = k0;
#pragma unroll
      for (int k = 2; k <= 64; k <<= 1) {
#pragma unroll
        for (int j = k >> 1; j > 0; j >>= 1) {
          u64 p = __shfl_xor(v, j);
          bool takeMin = (((lane & k) == 0) == ((lane & j) == 0));
          bool pl = p < v;
          u64 mnv = pl ? p : v;
          u64 mxv = pl ? v : p;
          v = takeMin ? mnv : mxv;
        }
      }
      if (lane < KK) outp[lane] = (int)(v & 8191ull);
    } else {
      bool v1 = ((u32)(lane + 64) < cnt);
      u32 m1 = v1 ? (u32)ssurv[qq][lane + 64] : 0u;
      double s1 = ddist(Qx, Qy, Qz, Qd2, X[m1 * 3], X[m1 * 3 + 1], X[m1 * 3 + 2]);
      u64 k1 = v1 ? ((sortable64(s1) & 0xFFFFFFFFFFFFE000ull) | (u64)m1) : ~0ull;
      u32 selm = 0;
      for (int r = 0; r < KK; ++r) {
        u64 mk = (k0 < k1) ? k0 : k1;
#pragma unroll
        for (int j = 32; j > 0; j >>= 1) {
          u64 p = __shfl_xor(mk, j);
          if (p < mk) mk = p;
        }
        if (k0 == mk) k0 = ~0ull;
        else if (k1 == mk) k1 = ~0ull;
        if (lane == r) selm = (u32)(mk & 8191ull);
      }
      if (lane < KK) outp[lane] = (int)selm;
    }
  }
}

// ---------- kB: feat GEMM with geo fused per-block (r10-verbatim) ----------
__global__ __launch_bounds__(256) void k_feat(
    const float* __restrict__ f, const u32* __restrict__ Wt32, const float* __restrict__ beta_f,
    const float* __restrict__ xyz, const float* __restrict__ Wgu, const float* __restrict__ Wgv,
    const float* __restrict__ beta_g, u32* __restrict__ ucat, u32* __restrict__ vcat) {
  __shared__ u32 sW[128 * 64];
  __shared__ float sF[128][68];

  const int t = threadIdx.x;
  const int blk = blockIdx.x;                 // 0..511
  const int H = blk & 1;                      // 0: u-half, 1: v-half
  const int b = blk >> 8;
  const int n0 = ((blk >> 1) & 127) << 6;
  const int boff = b * (NC * NN);

#pragma unroll
  for (int k = 0; k < 32; ++k) {
    int i = t + (k << 8);                     // 0..8191
    sW[i] = Wt32[((i >> 6) << 7) + (H << 6) + (i & 63)];
  }
#pragma unroll
  for (int k = 0; k < 32; ++k) {
    int i = t + (k << 8);
    int c = i >> 6, col = i & 63;
    sF[c][col] = f[boff + c * NN + n0 + col];
  }
  __syncthreads();

  const int w = t >> 6, lane = t & 63;
  const int og = lane >> 4, pg = lane & 15;
  const int o0 = (w << 5) + (og << 3);        // local channel 0..120 (step 8)
  const int p0 = pg << 2;                     // point 0..60 (step 4)

  float acc[8][4];
#pragma unroll
  for (int a = 0; a < 8; ++a)
#pragma unroll
    for (int p = 0; p < 4; ++p) acc[a][p] = 0.0f;

  for (int c = 0; c < 128; ++c) {
    float4 fa = *(const float4*)&sF[c][p0];
    uint4 wr = *(const uint4*)&sW[(c << 6) + (o0 >> 1)];
    float wv[8] = {bflo(wr.x), bfhi(wr.x), bflo(wr.y), bfhi(wr.y),
                   bflo(wr.z), bfhi(wr.z), bflo(wr.w), bfhi(wr.w)};
    float fv[4] = {fa.x, fa.y, fa.z, fa.w};
#pragma unroll
    for (int a = 0; a < 8; ++a)
#pragma unroll
      for (int p = 0; p < 4; ++p) acc[a][p] = __builtin_fmaf(wv[a], fv[p], acc[a][p]);
  }

  float bet[8];
#pragma unroll
  for (int a = 0; a < 8; ++a) bet[a] = (H == 0) ? beta_f[o0 + a] : 0.0f;
  u32* dstbase = (H == 0) ? ucat : vcat;
#pragma unroll
  for (int p = 0; p < 4; ++p) {
    int pt = (b << 13) + n0 + p0 + p;
    u32 d0 = (u32)f2bf(acc[0][p] + bet[0]) | ((u32)f2bf(acc[1][p] + bet[1]) << 16);
    u32 d1 = (u32)f2bf(acc[2][p] + bet[2]) | ((u32)f2bf(acc[3][p] + bet[3]) << 16);
    u32 d2 = (u32)f2bf(acc[4][p] + bet[4]) | ((u32)f2bf(acc[5][p] + bet[5]) << 16);
    u32 d3 = (u32)f2bf(acc[6][p] + bet[6]) | ((u32)f2bf(acc[7][p] + bet[7]) << 16);
    *(uint4*)&dstbase[pt * 128 + 64 + (o0 >> 1)] = make_uint4(d0, d1, d2, d3);
  }

  // ---- fused geo role: this block's 64 points, columns = this H half ----
  {
    const int oc = lane;                      // u32 column 0..63
    const float* Ws = (H == 0) ? Wgu : Wgv;
    const int o0g = oc * 2, o1g = oc * 2 + 1;
    float w0x = Ws[o0g * 3], w0y = Ws[o0g * 3 + 1], w0z = Ws[o0g * 3 + 2];
    float w1x = Ws[o1g * 3], w1y = Ws[o1g * 3 + 1], w1z = Ws[o1g * 3 + 2];
    float b0 = (H == 0) ? beta_g[o0g] : 0.0f;
    float b1 = (H == 0) ? beta_g[o1g] : 0.0f;
#pragma unroll 4
    for (int j = 0; j < 16; ++j) {
      int pt = n0 + (w << 4) + j;
      const float* xp = xyz + ((b << 13) + pt) * 3;
      float X = xp[0], Y = xp[1], Z = xp[2];
      float v0 = X * w0x + Y * w0y + Z * w0z + b0;
      float v1 = X * w1x + Y * w1y + Z * w1z + b1;
      dstbase[(((b << 13) + pt) << 7) + oc] =
          (u32)f2bf(v0) | ((u32)f2bf(v1) << 16);
    }
  }
}

// ---------- kC: gather + max + relu + transpose-write (r10-verbatim) ----------
__global__ __launch_bounds__(256) void k_gather(
    const u32* __restrict__ ucat, const u32* __restrict__ vcat,
    const int* __restrict__ knn, float* __restrict__ out) {
  __shared__ float tr[64 * 65];               // 16.6 KB

  const int t = threadIdx.x;
  const int blk = blockIdx.x;                 // 0..1023
  const int Q = blk & 3;                      // u32-column quarter
  const int b = blk >> 9;
  const int n0 = ((blk >> 2) & 127) << 6;
  const int w = t >> 6, lane = t & 63;
  const int half = lane >> 5;
  const int l32 = lane & 31;
  const int lo = (Q << 5) | l32;              // global u32 column 0..127

  for (int step = 0; step < 8; ++step) {
    int qq = (step << 3) + (w << 1) + half;   // 0..63
    int q = n0 + qq;
    const int* ip = knn + ((b << 13) + q) * KK;
    float a0 = -__builtin_inff(), a1 = -__builtin_inff();
#pragma unroll
    for (int k = 0; k < KK; ++k) {
      int p = ip[k];
      u32 d = vcat[(((b << 13) + p) << 7) + lo];
      a0 = fmaxf(a0, bflo(d));
      a1 = fmaxf(a1, bfhi(d));
    }
    u32 u = ucat[(((b << 13) + q) << 7) + lo];
    tr[qq * 65 + l32] = fmaxf(bflo(u) + a0, 0.0f);        // even local chans
    tr[qq * 65 + 32 + l32] = fmaxf(bfhi(u) + a1, 0.0f);   // odd local chans
  }
  __syncthreads();

  float* ob = out + b * (256 * NN) + (Q << 6) * NN;
  for (int i = 0; i < 16; ++i) {
    int o = (w << 4) + i;                     // local channel 0..63
    int col = ((o & 1) << 5) + (o >> 1);
    __builtin_nontemporal_store(tr[lane * 65 + col], &ob[o * NN + n0 + lane]);
  }
}

// ---------- launch ----------
extern "C" void kernel_launch(void* const* d_in, const int* in_sizes, int n_in,
                              void* d_out, int out_size, void* d_ws, size_t ws_size,
                              hipStream_t stream) {
  const float* xyz = (const float*)d_in[0];
  const float* f   = (const float*)d_in[1];
  const float* Wg  = (const float*)d_in[2];
  const float* gg  = (const float*)d_in[3];
  const float* bg  = (const float*)d_in[4];
  const float* mg  = (const float*)d_in[5];
  const float* vg  = (const float*)d_in[6];
  const float* Wf  = (const float*)d_in[7];
  const float* gf  = (const float*)d_in[8];
  const float* bf_ = (const float*)d_in[9];
  const float* mf  = (const float*)d_in[10];
  const float* vf  = (const float*)d_in[11];

  char* ws = (char*)d_ws;
  u16*   Wt     = (u16*)ws;                               // 65536 B
  float* beta_f = (float*)(ws + 65536);
  float* Wgu    = (float*)(ws + 66048);
  float* Wgv    = (float*)(ws + 67584);
  float* beta_g = (float*)(ws + 69120);
  u32*   ucat   = (u32*)(ws + 69632);                     // 8 MB
  u32*   vcat   = (u32*)(ws + 69632 + 8388608);           // 8 MB
  int*   knn    = (int*)(ws + 69632 + 2 * 8388608);       // 1.4 MB
  float* out    = (float*)d_out;

  if (ws_size < (size_t)(69632 + 2 * 8388608 + 16384 * KK * 4)) return;

  k_knnprep<<<dim3(288), dim3(1024), 0, stream>>>(
      xyz, knn, Wf, gf, bf_, mf, vf, Wg, gg, bg, mg, vg,
      Wt, beta_f, Wgu, Wgv, beta_g);
  k_feat<<<dim3(512), dim3(256), 0, stream>>>(
      f, (const u32*)Wt, beta_f, xyz, Wgu, Wgv, beta_g, ucat, vcat);
  k_gather<<<dim3(1024), dim3(256), 0, stream>>>(ucat, vcat, knn, out);
}

// Round 12
// 171.867 us; speedup vs baseline: 1.0551x; 1.0551x over previous
//
#include <hip/hip_runtime.h>

typedef unsigned int u32;
typedef unsigned long long u64;
typedef unsigned short u16;

#define DEV __device__ __forceinline__

// ---------- helpers ----------
DEV u16 f2bf(float x) {                      // fp32 -> bf16 RNE
  u32 u = __float_as_uint(x);
  u32 r = u + 0x7fffu + ((u >> 16) & 1u);
  return (u16)(r >> 16);
}
DEV float bflo(u32 d) { return __uint_as_float(d << 16); }
DEV float bfhi(u32 d) { return __uint_as_float(d & 0xffff0000u); }
DEV u64 sortable64(double f) {               // monotonic f64 -> u64
  long long b = __double_as_longlong(f);
  return (u64)b ^ (u64)((b >> 63) | (long long)0x8000000000000000ll);
}
// fp64 exact-selection distance (float products are exact in f64)
DEV double ddist(double qx, double qy, double qz, double qd2,
                 float mxf, float myf, float mzf) {
  double cx = (double)mxf, cy = (double)myf, cz = (double)mzf;
  double cd2 = cx * cx + cy * cy + cz * cz;
  double dot = cx * qx + cy * qy + cz * qz;
  return (qd2 + cd2) - 2.0 * dot;
}

#define NB 2
#define NN 8192
#define NC 128
#define KK 21
// screening metric: st = cd2 - 2*dot (qd2 dropped — per-query constant shift).
// fp32 error vs fp64 <= ~2e-4 on these operand scales; MARGIN covers it so the
// fp64 top-21 set provably survives fp32 screening.
#define MARGIN 1e-3f

// ---------- kA: exact KNN with prep distributed into block prologues ----------
// r7 single-stage core (proven 58.8us) with two contained fixes:
// (1) 256 blocks (not 288): at 148KB LDS = 1 block/CU, the extra 32 prep
//     blocks forced a second block generation on 32 CUs (tail = knn + prep).
//     Each block now folds 128 of the 32768 Wt entries in its prologue
//     (verbatim expressions -> bit-identical), hidden under staging loads.
// (2) pass-B 4-candidate grouping: one rare-taken branch per (query, 4 cands)
//     instead of per (query, cand) — cuts v_cmp/saveexec/branch overhead ~4x.
//     Same comparisons -> identical survivor set; selection unchanged.
__global__ __launch_bounds__(1024) void k_knnprep(
    const float* __restrict__ xyz, int* __restrict__ knn,
    const float* __restrict__ Wf, const float* __restrict__ gf, const float* __restrict__ bf_,
    const float* __restrict__ mf, const float* __restrict__ vf,
    const float* __restrict__ Wg, const float* __restrict__ gg, const float* __restrict__ bg,
    const float* __restrict__ mg, const float* __restrict__ vg,
    u16* __restrict__ Wt, float* __restrict__ beta_f,
    float* __restrict__ Wgu, float* __restrict__ Wgv, float* __restrict__ beta_g) {
  __shared__ float4 sc[NN];                   // 128 KB: all candidates (x,y,z,d2)
  __shared__ u16 ssurv[64][128];              // 16 KB
  __shared__ u32 scnt[64];

  const int t = threadIdx.x;

  // ---- prep slice: this block's 128 Wt entries (verbatim k_prep math) ----
  if (t < 128) {
    int g = (blockIdx.x << 7) + t;            // 0..32767 across the grid
    int c = g >> 8, o = g & 255;
    float val;
    if (o < 128) {
      float inv = gf[o] / sqrtf(vf[o] + 1e-5f);
      val = inv * (Wf[o * 256 + c] - Wf[o * 256 + c + 128]);
    } else {
      int o2 = o - 128;
      float inv = gf[o2] / sqrtf(vf[o2] + 1e-5f);
      val = inv * Wf[o2 * 256 + c + 128];
    }
    Wt[c * 256 + o] = f2bf(val);
    if (g < 128) {
      float inv = gf[g] / sqrtf(vf[g] + 1e-5f);
      beta_f[g] = bf_[g] - mf[g] * inv;
    } else if (g < 256) {
      int oo = g - 128;
      float invg = gg[oo] / sqrtf(vg[oo] + 1e-5f);
#pragma unroll
      for (int d = 0; d < 3; ++d) {
        Wgu[oo * 3 + d] = invg * (Wg[oo * 6 + d] - Wg[oo * 6 + 3 + d]);
        Wgv[oo * 3 + d] = invg * Wg[oo * 6 + 3 + d];
      }
      beta_g[oo] = bg[oo] - mg[oo] * invg;
    }
  }

  // ---- KNN role ----
  const int kb = blockIdx.x;                  // 0..255
  const int b = kb >> 7;                      // 128 blocks per batch
  const int n0 = (kb & 127) << 6;             // 64 queries per block
  const float* X = xyz + b * (NN * 3);

  if (t < 64) scnt[t] = 0u;

  const int w = t >> 6, lane = t & 63;        // w = 0..15

  // query coords (4 queries per wave); fold -2x for the fma chain
  float mx[4], my[4], mz[4];
#pragma unroll
  for (int i = 0; i < 4; ++i) {
    int q = n0 + (w << 2) + i;
    mx[i] = -2.0f * X[q * 3];
    my[i] = -2.0f * X[q * 3 + 1];
    mz[i] = -2.0f * X[q * 3 + 2];
  }

  // stage ALL candidates once (identical fma chain as before -> same bits)
#pragma unroll
  for (int k = 0; k < 8; ++k) {
    int c = (k << 10) + t;
    float x = X[c * 3], y = X[c * 3 + 1], z = X[c * 3 + 2];
    float d2 = __builtin_fmaf(x, x, __builtin_fmaf(y, y, z * z));
    sc[c] = make_float4(x, y, z, d2);
  }
  __syncthreads();                            // barrier #1 (of 2)

  // ---- pass A: per-lane running min of st = cd2 - 2*dot ----
  float mn[4];
#pragma unroll
  for (int i = 0; i < 4; ++i) mn[i] = __builtin_inff();

#pragma unroll 4
  for (int cc = 0; cc < NN; cc += 64) {
    float4 C = sc[cc + lane];
#pragma unroll
    for (int i = 0; i < 4; ++i) {
      float s = __builtin_fmaf(C.x, mx[i],
                __builtin_fmaf(C.y, my[i],
                __builtin_fmaf(C.z, mz[i], C.w)));
      mn[i] = fminf(mn[i], s);
    }
  }

  // ---- threshold: 21st smallest of 64 disjoint-subset lane minima ----
  // (any 21 of the minima witness 21 distinct candidates => upper bound on d21)
  float thr[4];
#pragma unroll
  for (int i = 0; i < 4; ++i) {
    float v = mn[i];
#pragma unroll
    for (int k = 2; k <= 64; k <<= 1) {
#pragma unroll
      for (int j = k >> 1; j > 0; j >>= 1) {
        float p = __shfl_xor(v, j);
        bool takeMin = (((lane & k) == 0) == ((lane & j) == 0));
        v = takeMin ? fminf(v, p) : fmaxf(v, p);
      }
    }
    thr[i] = __shfl(v, 20) + MARGIN;
  }

  // ---- pass B: compact survivors, 4-candidate groups (sc resident) ----
#pragma unroll 1
  for (int cc = 0; cc < NN; cc += 256) {
    float4 C0 = sc[cc + lane];
    float4 C1 = sc[cc + 64 + lane];
    float4 C2 = sc[cc + 128 + lane];
    float4 C3 = sc[cc + 192 + lane];
#pragma unroll
    for (int i = 0; i < 4; ++i) {
      float s0 = __builtin_fmaf(C0.x, mx[i],
                 __builtin_fmaf(C0.y, my[i],
                 __builtin_fmaf(C0.z, mz[i], C0.w)));
      float s1 = __builtin_fmaf(C1.x, mx[i],
                 __builtin_fmaf(C1.y, my[i],
                 __builtin_fmaf(C1.z, mz[i], C1.w)));
      float s2 = __builtin_fmaf(C2.x, mx[i],
                 __builtin_fmaf(C2.y, my[i],
                 __builtin_fmaf(C2.z, mz[i], C2.w)));
      float s3 = __builtin_fmaf(C3.x, mx[i],
                 __builtin_fmaf(C3.y, my[i],
                 __builtin_fmaf(C3.z, mz[i], C3.w)));
      float worst = fminf(fminf(s0, s1), fminf(s2, s3));
      if (worst <= thr[i]) {                  // one rare branch per (q, 4 cands)
        int qq = (w << 2) + i;
        if (s0 <= thr[i]) {
          u32 slot = atomicAdd(&scnt[qq], 1u);
          if (slot < 128u) ssurv[qq][slot] = (u16)(cc + lane);
        }
        if (s1 <= thr[i]) {
          u32 slot = atomicAdd(&scnt[qq], 1u);
          if (slot < 128u) ssurv[qq][slot] = (u16)(cc + 64 + lane);
        }
        if (s2 <= thr[i]) {
          u32 slot = atomicAdd(&scnt[qq], 1u);
          if (slot < 128u) ssurv[qq][slot] = (u16)(cc + 128 + lane);
        }
        if (s3 <= thr[i]) {
          u32 slot = atomicAdd(&scnt[qq], 1u);
          if (slot < 128u) ssurv[qq][slot] = (u16)(cc + 192 + lane);
        }
      }
    }
  }
  __syncthreads();                            // barrier #2 (of 2)

  // ---- selection: exact top-21 by fp64 (dist, idx); 4 queries per wave ----
#pragma unroll 1
  for (int i = 0; i < 4; ++i) {
    const int qq = (w << 2) + i;
    const int q = n0 + qq;
    double Qx = (double)X[q * 3], Qy = (double)X[q * 3 + 1], Qz = (double)X[q * 3 + 2];
    double Qd2 = Qx * Qx + Qy * Qy + Qz * Qz;
    u32 cnt = scnt[qq];
    int* outp = knn + ((b << 13) + q) * KK;

    bool v0 = ((u32)lane < cnt);
    u32 m0 = v0 ? (u32)ssurv[qq][lane] : 0u;
    double s0 = ddist(Qx, Qy, Qz, Qd2, X[m0 * 3], X[m0 * 3 + 1], X[m0 * 3 + 2]);
    // key: fp64-sortable, low 13 bits replaced by idx (lowest-index tie-break)
    u64 k0 = v0 ? ((sortable64(s0) & 0xFFFFFFFFFFFFE000ull) | (u64)m0) : ~0ull;

    if (cnt <= 64u) {
      u64 v = k0;
#pragma unroll
      for (int k = 2; k <= 64; k <<= 1) {
#pragma unroll
        for (int j = k >> 1; j > 0; j >>= 1) {
          u64 p = __shfl_xor(v, j);
          bool takeMin = (((lane & k) == 0) == ((lane & j) == 0));
          bool pl = p < v;
          u64 mnv = pl ? p : v;
          u64 mxv = pl ? v : p;
          v = takeMin ? mnv : mxv;
        }
      }
      if (lane < KK) outp[lane] = (int)(v & 8191ull);
    } else {
      bool v1 = ((u32)(lane + 64) < cnt);
      u32 m1 = v1 ? (u32)ssurv[qq][lane + 64] : 0u;
      double s1 = ddist(Qx, Qy, Qz, Qd2, X[m1 * 3], X[m1 * 3 + 1], X[m1 * 3 + 2]);
      u64 k1 = v1 ? ((sortable64(s1) & 0xFFFFFFFFFFFFE000ull) | (u64)m1) : ~0ull;
      u32 selm = 0;
      for (int r = 0; r < KK; ++r) {
        u64 mk = (k0 < k1) ? k0 : k1;
#pragma unroll
        for (int j = 32; j > 0; j >>= 1) {
          u64 p = __shfl_xor(mk, j);
          if (p < mk) mk = p;
        }
        if (k0 == mk) k0 = ~0ull;
        else if (k1 == mk) k1 = ~0ull;
        if (lane == r) selm = (u32)(mk & 8191ull);
      }
      if (lane < KK) outp[lane] = (int)selm;
    }
  }
}

// ---------- kB: feat GEMM with geo fused per-block (r10-verbatim) ----------
__global__ __launch_bounds__(256) void k_feat(
    const float* __restrict__ f, const u32* __restrict__ Wt32, const float* __restrict__ beta_f,
    const float* __restrict__ xyz, const float* __restrict__ Wgu, const float* __restrict__ Wgv,
    const float* __restrict__ beta_g, u32* __restrict__ ucat, u32* __restrict__ vcat) {
  __shared__ u32 sW[128 * 64];
  __shared__ float sF[128][68];

  const int t = threadIdx.x;
  const int blk = blockIdx.x;                 // 0..511
  const int H = blk & 1;                      // 0: u-half, 1: v-half
  const int b = blk >> 8;
  const int n0 = ((blk >> 1) & 127) << 6;
  const int boff = b * (NC * NN);

#pragma unroll
  for (int k = 0; k < 32; ++k) {
    int i = t + (k << 8);                     // 0..8191
    sW[i] = Wt32[((i >> 6) << 7) + (H << 6) + (i & 63)];
  }
#pragma unroll
  for (int k = 0; k < 32; ++k) {
    int i = t + (k << 8);
    int c = i >> 6, col = i & 63;
    sF[c][col] = f[boff + c * NN + n0 + col];
  }
  __syncthreads();

  const int w = t >> 6, lane = t & 63;
  const int og = lane >> 4, pg = lane & 15;
  const int o0 = (w << 5) + (og << 3);        // local channel 0..120 (step 8)
  const int p0 = pg << 2;                     // point 0..60 (step 4)

  float acc[8][4];
#pragma unroll
  for (int a = 0; a < 8; ++a)
#pragma unroll
    for (int p = 0; p < 4; ++p) acc[a][p] = 0.0f;

  for (int c = 0; c < 128; ++c) {
    float4 fa = *(const float4*)&sF[c][p0];
    uint4 wr = *(const uint4*)&sW[(c << 6) + (o0 >> 1)];
    float wv[8] = {bflo(wr.x), bfhi(wr.x), bflo(wr.y), bfhi(wr.y),
                   bflo(wr.z), bfhi(wr.z), bflo(wr.w), bfhi(wr.w)};
    float fv[4] = {fa.x, fa.y, fa.z, fa.w};
#pragma unroll
    for (int a = 0; a < 8; ++a)
#pragma unroll
      for (int p = 0; p < 4; ++p) acc[a][p] = __builtin_fmaf(wv[a], fv[p], acc[a][p]);
  }

  float bet[8];
#pragma unroll
  for (int a = 0; a < 8; ++a) bet[a] = (H == 0) ? beta_f[o0 + a] : 0.0f;
  u32* dstbase = (H == 0) ? ucat : vcat;
#pragma unroll
  for (int p = 0; p < 4; ++p) {
    int pt = (b << 13) + n0 + p0 + p;
    u32 d0 = (u32)f2bf(acc[0][p] + bet[0]) | ((u32)f2bf(acc[1][p] + bet[1]) << 16);
    u32 d1 = (u32)f2bf(acc[2][p] + bet[2]) | ((u32)f2bf(acc[3][p] + bet[3]) << 16);
    u32 d2 = (u32)f2bf(acc[4][p] + bet[4]) | ((u32)f2bf(acc[5][p] + bet[5]) << 16);
    u32 d3 = (u32)f2bf(acc[6][p] + bet[6]) | ((u32)f2bf(acc[7][p] + bet[7]) << 16);
    *(uint4*)&dstbase[pt * 128 + 64 + (o0 >> 1)] = make_uint4(d0, d1, d2, d3);
  }

  // ---- fused geo role: this block's 64 points, columns = this H half ----
  {
    const int oc = lane;                      // u32 column 0..63
    const float* Ws = (H == 0) ? Wgu : Wgv;
    const int o0g = oc * 2, o1g = oc * 2 + 1;
    float w0x = Ws[o0g * 3], w0y = Ws[o0g * 3 + 1], w0z = Ws[o0g * 3 + 2];
    float w1x = Ws[o1g * 3], w1y = Ws[o1g * 3 + 1], w1z = Ws[o1g * 3 + 2];
    float b0 = (H == 0) ? beta_g[o0g] : 0.0f;
    float b1 = (H == 0) ? beta_g[o1g] : 0.0f;
#pragma unroll 4
    for (int j = 0; j < 16; ++j) {
      int pt = n0 + (w << 4) + j;
      const float* xp = xyz + ((b << 13) + pt) * 3;
      float X = xp[0], Y = xp[1], Z = xp[2];
      float v0 = X * w0x + Y * w0y + Z * w0z + b0;
      float v1 = X * w1x + Y * w1y + Z * w1z + b1;
      dstbase[(((b << 13) + pt) << 7) + oc] =
          (u32)f2bf(v0) | ((u32)f2bf(v1) << 16);
    }
  }
}

// ---------- kC: gather + max + relu + transpose-write (r10-verbatim) ----------
__global__ __launch_bounds__(256) void k_gather(
    const u32* __restrict__ ucat, const u32* __restrict__ vcat,
    const int* __restrict__ knn, float* __restrict__ out) {
  __shared__ float tr[64 * 65];               // 16.6 KB

  const int t = threadIdx.x;
  const int blk = blockIdx.x;                 // 0..1023
  const int Q = blk & 3;                      // u32-column quarter
  const int b = blk >> 9;
  const int n0 = ((blk >> 2) & 127) << 6;
  const int w = t >> 6, lane = t & 63;
  const int half = lane >> 5;
  const int l32 = lane & 31;
  const int lo = (Q << 5) | l32;              // global u32 column 0..127

  for (int step = 0; step < 8; ++step) {
    int qq = (step << 3) + (w << 1) + half;   // 0..63
    int q = n0 + qq;
    const int* ip = knn + ((b << 13) + q) * KK;
    float a0 = -__builtin_inff(), a1 = -__builtin_inff();
#pragma unroll
    for (int k = 0; k < KK; ++k) {
      int p = ip[k];
      u32 d = vcat[(((b << 13) + p) << 7) + lo];
      a0 = fmaxf(a0, bflo(d));
      a1 = fmaxf(a1, bfhi(d));
    }
    u32 u = ucat[(((b << 13) + q) << 7) + lo];
    tr[qq * 65 + l32] = fmaxf(bflo(u) + a0, 0.0f);        // even local chans
    tr[qq * 65 + 32 + l32] = fmaxf(bfhi(u) + a1, 0.0f);   // odd local chans
  }
  __syncthreads();

  float* ob = out + b * (256 * NN) + (Q << 6) * NN;
  for (int i = 0; i < 16; ++i) {
    int o = (w << 4) + i;                     // local channel 0..63
    int col = ((o & 1) << 5) + (o >> 1);
    __builtin_nontemporal_store(tr[lane * 65 + col], &ob[o * NN + n0 + lane]);
  }
}

// ---------- launch ----------
extern "C" void kernel_launch(void* const* d_in, const int* in_sizes, int n_in,
                              void* d_out, int out_size, void* d_ws, size_t ws_size,
                              hipStream_t stream) {
  const float* xyz = (const float*)d_in[0];
  const float* f   = (const float*)d_in[1];
  const float* Wg  = (const float*)d_in[2];
  const float* gg  = (const float*)d_in[3];
  const float* bg  = (const float*)d_in[4];
  const float* mg  = (const float*)d_in[5];
  const float* vg  = (const float*)d_in[6];
  const float* Wf  = (const float*)d_in[7];
  const float* gf  = (const float*)d_in[8];
  const float* bf_ = (const float*)d_in[9];
  const float* mf  = (const float*)d_in[10];
  const float* vf  = (const float*)d_in[11];

  char* ws = (char*)d_ws;
  u16*   Wt     = (u16*)ws;                               // 65536 B
  float* beta_f = (float*)(ws + 65536);
  float* Wgu    = (float*)(ws + 66048);
  float* Wgv    = (float*)(ws + 67584);
  float* beta_g = (float*)(ws + 69120);
  u32*   ucat   = (u32*)(ws + 69632);                     // 8 MB
  u32*   vcat   = (u32*)(ws + 69632 + 8388608);           // 8 MB
  int*   knn    = (int*)(ws + 69632 + 2 * 8388608);       // 1.4 MB
  float* out    = (float*)d_out;

  if (ws_size < (size_t)(69632 + 2 * 8388608 + 16384 * KK * 4)) return;

  k_knnprep<<<dim3(256), dim3(1024), 0, stream>>>(
      xyz, knn, Wf, gf, bf_, mf, vf, Wg, gg, bg, mg, vg,
      Wt, beta_f, Wgu, Wgv, beta_g);
  k_feat<<<dim3(512), dim3(256), 0, stream>>>(
      f, (const u32*)Wt, beta_f, xyz, Wgu, Wgv, beta_g, ucat, vcat);
  k_gather<<<dim3(1024), dim3(256), 0, stream>>>(ucat, vcat, knn, out);
}